// Round 10
// baseline (445.682 us; speedup 1.0000x reference)
//
#include <hip/hip_runtime.h>

#define NN  100000
#define EE1 1600000
#define EE2 1600000

#define NPB 256                          // nodes per bucket
#define NB  ((NN + NPB - 1) / NPB)       // 391 buckets
#define BCAP 4608                        // fixed slots per bucket (mean 4092 + 8 sigma)
#define EMAX (NB * BCAP)                 // 1,801,728 gapped csr slots
#define EPB 4096                         // edges per block (binA)
#define NABLK ((EE1 + EPB - 1) / EPB)    // 391 blocks

typedef unsigned short u16;
typedef unsigned int   u32;
typedef short s16x8 __attribute__((ext_vector_type(8)));
typedef float f32x4 __attribute__((ext_vector_type(4)));

__device__ __forceinline__ float bf2f(u32 u) {
    union { u32 i; float f; } v; v.i = (u & 0xffffu) << 16; return v.f;
}
__device__ __forceinline__ u16 f2bf(float f) {
    u32 x = __builtin_bit_cast(u32, f);
    return (u16)((x + 0x7fffu + ((x >> 16) & 1u)) >> 16);
}
__device__ __forceinline__ u32 pack2(float a, float b) {
    return (u32)f2bf(a) | ((u32)f2bf(b) << 16);
}
__device__ __forceinline__ int clampi(int v, int hi) {
    return v < 0 ? 0 : (v > hi ? hi : v);
}

// ---------------- fused preamble: X->bf16 cast + weight swizzle + bias blob + bcur init ----------------
__global__ void k_pre(const float* __restrict__ X, u16* __restrict__ Xb,
                      const float* __restrict__ Ws1, const float* __restrict__ Wn1,
                      const float* __restrict__ Ws2, const float* __restrict__ Wn2,
                      const float* __restrict__ Wm1,
                      u16* __restrict__ WT1, u16* __restrict__ WT2, u16* __restrict__ WTM,
                      const float* __restrict__ b1, const float* __restrict__ b2,
                      const float* __restrict__ bm1, const float* __restrict__ w2,
                      const float* __restrict__ b2m,
                      float* __restrict__ blob, int* __restrict__ bcur) {
    int i = blockIdx.x * 256 + threadIdx.x;
    if (i < NN * 128 / 4) {                   // cast: 4 elements per thread
        float4 v = *(const float4*)&X[i * 4];
        union { u16 h[4]; uint2 u; } o;
        o.h[0] = f2bf(v.x); o.h[1] = f2bf(v.y);
        o.h[2] = f2bf(v.z); o.h[3] = f2bf(v.w);
        *(uint2*)&Xb[i * 4] = o.u;
    }
    if (i < 65536) {                          // weight swizzle into MFMA B-fragment order
        if (i < 32768) {                      // WT1: Kv=256 ([Ws1;Wn1]), CO=128
            int f = i, j = f & 7, L = (f >> 3) & 63, t2 = f >> 9;
            int s = t2 & 7, c = t2 >> 3;
            int k = s * 32 + ((L >> 4) << 3) + j, co = (c << 4) + (L & 15);
            WT1[f] = f2bf((k < 128) ? Ws1[k * 128 + co] : Wn1[(k - 128) * 128 + co]);
        } else if (i < 49152) {               // WT2: Kv=256 ([Ws2;Wn2]), CO=64
            int f = i - 32768, j = f & 7, L = (f >> 3) & 63, t2 = f >> 9;
            int s = t2 & 7, c = t2 >> 3;
            int k = s * 32 + ((L >> 4) << 3) + j, co = (c << 4) + (L & 15);
            WT2[f] = f2bf((k < 128) ? Ws2[k * 64 + co] : Wn2[(k - 128) * 64 + co]);
        } else {                              // WTM: K=128, CO=128 (Wmlp1 straight)
            int f = i - 49152, j = f & 7, L = (f >> 3) & 63, t2 = f >> 9;
            int s = t2 & 3, c = t2 >> 2;
            int k = s * 32 + ((L >> 4) << 3) + j, co = (c << 4) + (L & 15);
            WTM[f] = f2bf(Wm1[k * 128 + co]);
        }
    }
    if (i < NB) bcur[i] = i * BCAP;           // fixed bucket bases
    if (i < 449) {                            // bias blob
        if (i < 128)      blob[i] = b1[i];
        else if (i < 192) blob[i] = b2[i - 128];
        else if (i < 320) blob[i] = bm1[i - 192];
        else if (i < 448) blob[i] = w2[i - 320];
        else              blob[i] = b2m[0];
    }
}

// ================= CSR build: fixed-capacity buckets (no global scan) =================

// ---- A: scatter edges into fixed bucket regions, block-reserved runs ----
// packed entry: (dst & 255) << 24 | src   (src <= NN-1 < 2^24)
__global__ __launch_bounds__(256) void k_binA(const int* __restrict__ es,
                                              const int* __restrict__ ed,
                                              int* __restrict__ bucketCur,
                                              u32* __restrict__ buck) {
    __shared__ int hist[NB];
    __shared__ int base[NB];
    const int t = threadIdx.x;
    for (int i = t; i < NB; i += 256) hist[i] = 0;
    __syncthreads();
    const int e0 = blockIdx.x * EPB;
    const int e1 = min(e0 + EPB, EE1);
    for (int e = e0 + t; e < e1; e += 256)
        atomicAdd(&hist[clampi(ed[e], NN - 1) >> 8], 1);
    __syncthreads();
    for (int i = t; i < NB; i += 256) {
        const int h = hist[i];
        base[i] = h ? atomicAdd(&bucketCur[i], h) : 0;   // reserve contiguous run
        hist[i] = 0;                                     // reuse as running cursor
    }
    __syncthreads();
    for (int e = e0 + t; e < e1; e += 256) {
        const int d = clampi(ed[e], NN - 1);
        const int s = clampi(es[e], NN - 1);
        const int b = d >> 8;
        const int p = base[b] + atomicAdd(&hist[b], 1);
        if (p < (b + 1) * BCAP)                          // 8-sigma overflow guard
            buck[p] = ((u32)(d & 255) << 24) | (u32)s;
    }
}

// ---- B: per-bucket CSR fill + offs/ends. csr keeps the PACKED entry.
__global__ __launch_bounds__(256) void k_binB(const u32* __restrict__ buck,
                                              const int* __restrict__ bcur,
                                              int* __restrict__ offs,
                                              int* __restrict__ ends,
                                              u32* __restrict__ csr) {
    __shared__ int hist[NPB];
    __shared__ int scan[NPB];
    const int t = threadIdx.x;
    const int b = blockIdx.x;
    const int base = b * BCAP;
    int end = bcur[b];
    if (end > base + BCAP) end = base + BCAP;
    hist[t] = 0;
    __syncthreads();
    for (int i = base + t; i < end; i += 256)
        atomicAdd(&hist[buck[i] >> 24], 1);
    __syncthreads();
    const int v = hist[t];
    scan[t] = v;
    __syncthreads();
    for (int d = 1; d < 256; d <<= 1) {
        int x = (t >= d) ? scan[t - d] : 0;
        __syncthreads();
        scan[t] += x;
        __syncthreads();
    }
    const int excl = scan[t] - v;        // bucket-local exclusive prefix
    const int node = b * NPB + t;
    if (node < NN) {
        offs[node] = base + excl;        // begin
        ends[node] = base + scan[t];     // end (inclusive prefix)
    }
    hist[t] = base + excl;               // cursor for this node
    __syncthreads();
    for (int i = base + t; i < end; i += 256) {
        const u32 pv = buck[i];
        const int p = atomicAdd(&hist[pv >> 24], 1);   // LDS atomic
        csr[p] = pv;                                    // keep packed
    }
}

__device__ __forceinline__ void acc8(float* a, uint4 r) {
    a[0] += bf2f(r.x); a[1] += bf2f(r.x >> 16);
    a[2] += bf2f(r.y); a[3] += bf2f(r.y >> 16);
    a[4] += bf2f(r.z); a[5] += bf2f(r.z >> 16);
    a[6] += bf2f(r.w); a[7] += bf2f(r.w >> 16);
}

// ---------------- fused SAGE layer (bf16 in): H = relu([X | mean_agg(X)] @ [Ws;Wn] + b) ----------------
// 1024-thread blocks over a 64-node tile: 64 groups x 16 lanes, EXACTLY ONE
// node per group (no serial multi-node loop — R6 lever applied again).
// Phase B: MFMA tiling split across 16 waves (w>>2 = row stripe, w&3 = col group).
template<int CO, bool DUALOUT>
__global__ __launch_bounds__(1024) void k_layer(const u16* __restrict__ Xb,
                                                const u16* __restrict__ WT,
                                                const int* __restrict__ offs,
                                                const int* __restrict__ ends,
                                                const u32* __restrict__ csr,
                                                const float* __restrict__ biasf,
                                                u16* __restrict__ Hb,
                                                float* __restrict__ Hf) {
    constexpr int K = 128, KV = 8, CT = CO / 16, CH = CT / 4, RS = K + 8;
    __shared__ __align__(16) u16 aggT[64 * RS];
    const int t = threadIdx.x, lane = t & 63, w = t >> 6;
    const int grp = t >> 4, f = t & 15;         // group 0..63 owns node rbase+grp
    const int rbase = blockIdx.x * 64;

    // phase A: pull-aggregate neighbor mean for THIS group's single node
    {
        const int node = rbase + grp;
        float acc[8] = {0.f, 0.f, 0.f, 0.f, 0.f, 0.f, 0.f, 0.f};
        float sc = 0.f;
        if (node < NN) {
            int beg = offs[node], end = ends[node];
            if (beg < 0) beg = 0;
            if (end > EMAX) end = EMAX;
            if (end < beg) end = beg;
            sc = 1.0f / (float)max(end - beg, 1);
            int e = beg;
            for (; e + 4 <= end; e += 4) {
                u32 p0 = csr[e], p1 = csr[e + 1], p2 = csr[e + 2], p3 = csr[e + 3];
                uint4 r0 = *(const uint4*)&Xb[(size_t)(p0 & 0xFFFFFFu) * K + f * 8];
                uint4 r1 = *(const uint4*)&Xb[(size_t)(p1 & 0xFFFFFFu) * K + f * 8];
                uint4 r2 = *(const uint4*)&Xb[(size_t)(p2 & 0xFFFFFFu) * K + f * 8];
                uint4 r3 = *(const uint4*)&Xb[(size_t)(p3 & 0xFFFFFFu) * K + f * 8];
                acc8(acc, r0); acc8(acc, r1); acc8(acc, r2); acc8(acc, r3);
            }
            for (; e < end; ++e) {
                u32 p = csr[e];
                uint4 r = *(const uint4*)&Xb[(size_t)(p & 0xFFFFFFu) * K + f * 8];
                acc8(acc, r);
            }
        }
        uint4 o;
        o.x = pack2(acc[0] * sc, acc[1] * sc);
        o.y = pack2(acc[2] * sc, acc[3] * sc);
        o.z = pack2(acc[4] * sc, acc[5] * sc);
        o.w = pack2(acc[6] * sc, acc[7] * sc);
        *(uint4*)&aggT[grp * RS + f * 8] = o;
    }
    __syncthreads();

    // phase B: MFMA over virtual K=256 ([x_row | agg_row]); 16 waves:
    // row stripe ws = w>>2 (0..3), column group cq = w&3 (CH tiles each).
    const int nidx = lane & 15, quad = lane >> 4;
    const int ws = w >> 2, cq = w & 3;
    int arow = rbase + ws * 16 + nidx;
    if (arow > NN - 1) arow = NN - 1;          // clamped rows never stored
    const u16* xu = &Xb[(size_t)arow * K];
    const u16* grow = &aggT[(ws * 16 + nidx) * RS];
    f32x4 accv[CH] = {};
#pragma unroll
    for (int s = 0; s < KV; ++s) {
        s16x8 a = (s < 4) ? *(const s16x8*)&xu[s * 32 + quad * 8]
                          : *(const s16x8*)&grow[(s - 4) * 32 + quad * 8];
#pragma unroll
        for (int c = 0; c < CH; ++c) {
            const int cc = cq * CH + c;
            s16x8 b = *(const s16x8*)&WT[((cc * KV + s) * 64 + lane) * 8];
            accv[c] = __builtin_amdgcn_mfma_f32_16x16x32_bf16(a, b, accv[c], 0, 0, 0);
        }
    }
#pragma unroll
    for (int c = 0; c < CH; ++c) {
        const int col = (cq * CH + c) * 16 + nidx;
        float bv = biasf[col];
#pragma unroll
        for (int r = 0; r < 4; ++r) {
            int orow = rbase + ws * 16 + quad * 4 + r;
            if (orow < NN) {
                float hv = fmaxf(accv[c][r] + bv, 0.f);
                Hb[(size_t)orow * CO + col] = f2bf(hv);
                if (DUALOUT) Hf[(size_t)orow * CO + col] = hv;   // fp32 h output
            }
        }
    }
}

// ---------------- edge scoring via MFMA, 4 tiles (64 edges) per wave ----------------
// WTM (32 KB) staged in LDS once per block: removes the per-wave full-WTM
// re-read (~800 MB/dispatch of L1/L2 traffic) and frees L1 for the H2 gathers.
__global__ __launch_bounds__(256) void k_edge(const u16* __restrict__ H2,
                                              const u16* __restrict__ WTM,
                                              const int* __restrict__ es, const int* __restrict__ ed,
                                              const float* __restrict__ blob,
                                              float* __restrict__ out) {
    __shared__ __align__(16) u16 wlds[16384];      // 32 KB = full WTM
    const int t = threadIdx.x, lane = t & 63, w = t >> 6;
    const int nidx = lane & 15, quad = lane >> 4;
    const int base = blockIdx.x * 256 + w * 64;    // this wave: edges [base, base+64)

    // cooperative WTM -> LDS (256 threads x 8 x 16B, coalesced)
#pragma unroll
    for (int i = 0; i < 8; ++i)
        ((uint4*)wlds)[t + i * 256] = ((const uint4*)WTM)[t + i * 256];

    // 8 independent index loads
    const u16* rs[4];
    const u16* rd[4];
#pragma unroll
    for (int tt = 0; tt < 4; ++tt) {
        const int e = base + tt * 16 + nidx;
        const int ns = clampi(es[e], NN - 1);
        const int nd = clampi(ed[e], NN - 1);
        rs[tt] = H2 + (size_t)ns * 64;
        rd[tt] = H2 + (size_t)nd * 64;
    }
    // 16 independent 16B gathers, all in flight together
    s16x8 a[4][4];
#pragma unroll
    for (int tt = 0; tt < 4; ++tt) {
        a[tt][0] = *(const s16x8*)&rs[tt][     quad * 8];
        a[tt][1] = *(const s16x8*)&rs[tt][32 + quad * 8];
        a[tt][2] = *(const s16x8*)&rd[tt][     quad * 8];
        a[tt][3] = *(const s16x8*)&rd[tt][32 + quad * 8];
    }
    __syncthreads();                               // wlds ready

    float sum[4][4] = {};
#pragma unroll
    for (int c = 0; c < 8; ++c) {
        const s16x8 b0 = *(const s16x8*)&wlds[((c * 4 + 0) * 64 + lane) * 8];
        const s16x8 b1 = *(const s16x8*)&wlds[((c * 4 + 1) * 64 + lane) * 8];
        const s16x8 b2 = *(const s16x8*)&wlds[((c * 4 + 2) * 64 + lane) * 8];
        const s16x8 b3 = *(const s16x8*)&wlds[((c * 4 + 3) * 64 + lane) * 8];
        const int col = c * 16 + nidx;
        const float bb = blob[192 + col], ww = blob[320 + col];
#pragma unroll
        for (int tt = 0; tt < 4; ++tt) {
            f32x4 acc = {};
            acc = __builtin_amdgcn_mfma_f32_16x16x32_bf16(a[tt][0], b0, acc, 0, 0, 0);
            acc = __builtin_amdgcn_mfma_f32_16x16x32_bf16(a[tt][1], b1, acc, 0, 0, 0);
            acc = __builtin_amdgcn_mfma_f32_16x16x32_bf16(a[tt][2], b2, acc, 0, 0, 0);
            acc = __builtin_amdgcn_mfma_f32_16x16x32_bf16(a[tt][3], b3, acc, 0, 0, 0);
#pragma unroll
            for (int r = 0; r < 4; ++r)
                sum[tt][r] += fmaxf(acc[r] + bb, 0.f) * ww;
        }
    }

#pragma unroll
    for (int tt = 0; tt < 4; ++tt) {
#pragma unroll
        for (int r = 0; r < 4; ++r) {
            sum[tt][r] += __shfl_xor(sum[tt][r], 1, 64);
            sum[tt][r] += __shfl_xor(sum[tt][r], 2, 64);
            sum[tt][r] += __shfl_xor(sum[tt][r], 4, 64);
            sum[tt][r] += __shfl_xor(sum[tt][r], 8, 64);
        }
    }
    if (nidx == 0) {
        const float bb2 = blob[448];
#pragma unroll
        for (int tt = 0; tt < 4; ++tt) {
            f32x4 o;
#pragma unroll
            for (int r = 0; r < 4; ++r) {
                float x = sum[tt][r] + bb2;
                o[r] = 1.f / (1.f + __expf(-x));
            }
            *(f32x4*)&out[base + tt * 16 + quad * 4] = o;
        }
    }
}

extern "C" void kernel_launch(void* const* d_in, const int* in_sizes, int n_in,
                              void* d_out, int out_size, void* d_ws, size_t ws_size,
                              hipStream_t stream) {
    const float* X      = (const float*)d_in[0];
    const int*   esrc   = (const int*)d_in[1];
    const int*   edst   = (const int*)d_in[2];
    const int*   ssrc   = (const int*)d_in[3];
    const int*   sdst   = (const int*)d_in[4];
    const float* Wself1 = (const float*)d_in[5];
    const float* Wneigh1= (const float*)d_in[6];
    const float* b1     = (const float*)d_in[7];
    const float* Wself2 = (const float*)d_in[8];
    const float* Wneigh2= (const float*)d_in[9];
    const float* b2     = (const float*)d_in[10];
    const float* Wmlp1  = (const float*)d_in[11];
    const float* bmlp1  = (const float*)d_in[12];
    const float* Wmlp2  = (const float*)d_in[13];
    const float* bmlp2  = (const float*)d_in[14];

    // ---- workspace (ws_size >= 50 MB): peak 46.54 MB ----
    char* ws = (char*)d_ws;
    int*   offs = (int*)(ws + 0);             //   400,004 -> pad 400,128
    int*   ends = (int*)(ws + 400128);        //   400,000 -> pad 800,256
    u32*   csr  = (u32*)(ws + 800256);        // 7,206,912 (gapped, NB*BCAP) -> 8,007,168
    u16*   WTM  = (u16*)(ws + 8007168);       //    32,768 -> 8,039,936
    u16*   WT1  = (u16*)(ws + 8039936);       //    65,536 -> 8,105,472
    u16*   WT2  = (u16*)(ws + 8105472);       //    32,768 -> 8,138,240
    float* blob = (float*)(ws + 8138240);     //     1,796 -> pad 8,140,288
    u16*   H1   = (u16*)(ws + 8140288);       // 25,600,000 -> 33,740,288 (bf16 intern)
    u16*   H2b  = (u16*)(ws + 33740288);      // 12,800,000 -> 46,540,288 (bf16 copy of h)
    // bucket-sort scratch aliases H1 (dead before k_layer1 writes H1):
    u32*   buck = (u32*)(ws + 8140288);       // 7,206,912 -> 15,347,200
    int*   bcur = (int*)(ws + 15347200);      // 1,564

    // ---- OUTPUT: fp32 buffer, out_size=8M floats: [score 1.6M | h 6.4M] ----
    float* outScore = (float*)d_out;               // [EE2]
    float* Hf       = (float*)d_out + EE2;         // [NN*64]
    u16*   Xb       = (u16*)((char*)d_out + 6400000);   // 25.6 MB, ends at 32 MB

    k_pre<<<(NN * 128 / 4 + 255) / 256, 256, 0, stream>>>(
        X, Xb, Wself1, Wneigh1, Wself2, Wneigh2, Wmlp1, WT1, WT2, WTM,
        b1, b2, bmlp1, Wmlp2, bmlp2, blob, bcur);
    k_binA<<<NABLK, 256, 0, stream>>>(esrc, edst, bcur, buck);
    k_binB<<<NB, 256, 0, stream>>>(buck, bcur, offs, ends, csr);

    const int nblk = (NN + 63) / 64;
    k_layer<128, false><<<nblk, 1024, 0, stream>>>(Xb, WT1, offs, ends, csr, blob,       H1,  nullptr);
    k_layer<64,  true> <<<nblk, 1024, 0, stream>>>(H1, WT2, offs, ends, csr, blob + 128, H2b, Hf);
    k_edge<<<EE2 / 256, 256, 0, stream>>>(H2b, WTM, ssrc, sdst, blob, outScore);
}

// Round 11
// 444.396 us; speedup vs baseline: 1.0029x; 1.0029x over previous
//
#include <hip/hip_runtime.h>

#define NN  100000
#define EE1 1600000
#define EE2 1600000

#define NPB 256                          // nodes per bucket
#define NB  ((NN + NPB - 1) / NPB)       // 391 buckets
#define BCAP 4608                        // fixed slots per bucket (mean 4092 + 8 sigma)
#define EMAX (NB * BCAP)                 // 1,801,728 gapped csr slots
#define EPB 4096                         // edges per block (binA)
#define NABLK ((EE1 + EPB - 1) / EPB)    // 391 blocks

typedef unsigned short u16;
typedef unsigned int   u32;
typedef short s16x8 __attribute__((ext_vector_type(8)));
typedef float f32x4 __attribute__((ext_vector_type(4)));

__device__ __forceinline__ float bf2f(u32 u) {
    union { u32 i; float f; } v; v.i = (u & 0xffffu) << 16; return v.f;
}
__device__ __forceinline__ u16 f2bf(float f) {
    u32 x = __builtin_bit_cast(u32, f);
    return (u16)((x + 0x7fffu + ((x >> 16) & 1u)) >> 16);
}
__device__ __forceinline__ u32 pack2(float a, float b) {
    return (u32)f2bf(a) | ((u32)f2bf(b) << 16);
}
__device__ __forceinline__ int clampi(int v, int hi) {
    return v < 0 ? 0 : (v > hi ? hi : v);
}

// ---------------- fused preamble: X->bf16 cast + weight swizzle + bias blob + bcur init ----------------
__global__ void k_pre(const float* __restrict__ X, u16* __restrict__ Xb,
                      const float* __restrict__ Ws1, const float* __restrict__ Wn1,
                      const float* __restrict__ Ws2, const float* __restrict__ Wn2,
                      const float* __restrict__ Wm1,
                      u16* __restrict__ WT1, u16* __restrict__ WT2, u16* __restrict__ WTM,
                      const float* __restrict__ b1, const float* __restrict__ b2,
                      const float* __restrict__ bm1, const float* __restrict__ w2,
                      const float* __restrict__ b2m,
                      float* __restrict__ blob, int* __restrict__ bcur) {
    int i = blockIdx.x * 256 + threadIdx.x;
    if (i < NN * 128 / 4) {                   // cast: 4 elements per thread
        float4 v = *(const float4*)&X[i * 4];
        union { u16 h[4]; uint2 u; } o;
        o.h[0] = f2bf(v.x); o.h[1] = f2bf(v.y);
        o.h[2] = f2bf(v.z); o.h[3] = f2bf(v.w);
        *(uint2*)&Xb[i * 4] = o.u;
    }
    if (i < 65536) {                          // weight swizzle into MFMA B-fragment order
        if (i < 32768) {                      // WT1: Kv=256 ([Ws1;Wn1]), CO=128
            int f = i, j = f & 7, L = (f >> 3) & 63, t2 = f >> 9;
            int s = t2 & 7, c = t2 >> 3;
            int k = s * 32 + ((L >> 4) << 3) + j, co = (c << 4) + (L & 15);
            WT1[f] = f2bf((k < 128) ? Ws1[k * 128 + co] : Wn1[(k - 128) * 128 + co]);
        } else if (i < 49152) {               // WT2: Kv=256 ([Ws2;Wn2]), CO=64
            int f = i - 32768, j = f & 7, L = (f >> 3) & 63, t2 = f >> 9;
            int s = t2 & 7, c = t2 >> 3;
            int k = s * 32 + ((L >> 4) << 3) + j, co = (c << 4) + (L & 15);
            WT2[f] = f2bf((k < 128) ? Ws2[k * 64 + co] : Wn2[(k - 128) * 64 + co]);
        } else {                              // WTM: K=128, CO=128 (Wmlp1 straight)
            int f = i - 49152, j = f & 7, L = (f >> 3) & 63, t2 = f >> 9;
            int s = t2 & 3, c = t2 >> 2;
            int k = s * 32 + ((L >> 4) << 3) + j, co = (c << 4) + (L & 15);
            WTM[f] = f2bf(Wm1[k * 128 + co]);
        }
    }
    if (i < NB) bcur[i] = i * BCAP;           // fixed bucket bases
    if (i < 449) {                            // bias blob
        if (i < 128)      blob[i] = b1[i];
        else if (i < 192) blob[i] = b2[i - 128];
        else if (i < 320) blob[i] = bm1[i - 192];
        else if (i < 448) blob[i] = w2[i - 320];
        else              blob[i] = b2m[0];
    }
}

// ================= CSR build: fixed-capacity buckets (no global scan) =================

// ---- A: scatter edges into fixed bucket regions, block-reserved runs ----
// packed entry: (dst & 255) << 24 | src   (src <= NN-1 < 2^24)
__global__ __launch_bounds__(256) void k_binA(const int* __restrict__ es,
                                              const int* __restrict__ ed,
                                              int* __restrict__ bucketCur,
                                              u32* __restrict__ buck) {
    __shared__ int hist[NB];
    __shared__ int base[NB];
    const int t = threadIdx.x;
    for (int i = t; i < NB; i += 256) hist[i] = 0;
    __syncthreads();
    const int e0 = blockIdx.x * EPB;
    const int e1 = min(e0 + EPB, EE1);
    for (int e = e0 + t; e < e1; e += 256)
        atomicAdd(&hist[clampi(ed[e], NN - 1) >> 8], 1);
    __syncthreads();
    for (int i = t; i < NB; i += 256) {
        const int h = hist[i];
        base[i] = h ? atomicAdd(&bucketCur[i], h) : 0;   // reserve contiguous run
        hist[i] = 0;                                     // reuse as running cursor
    }
    __syncthreads();
    for (int e = e0 + t; e < e1; e += 256) {
        const int d = clampi(ed[e], NN - 1);
        const int s = clampi(es[e], NN - 1);
        const int b = d >> 8;
        const int p = base[b] + atomicAdd(&hist[b], 1);
        if (p < (b + 1) * BCAP)                          // 8-sigma overflow guard
            buck[p] = ((u32)(d & 255) << 24) | (u32)s;
    }
}

// ---- B: per-bucket CSR fill + offs/ends. csr keeps the PACKED entry.
__global__ __launch_bounds__(256) void k_binB(const u32* __restrict__ buck,
                                              const int* __restrict__ bcur,
                                              int* __restrict__ offs,
                                              int* __restrict__ ends,
                                              u32* __restrict__ csr) {
    __shared__ int hist[NPB];
    __shared__ int scan[NPB];
    const int t = threadIdx.x;
    const int b = blockIdx.x;
    const int base = b * BCAP;
    int end = bcur[b];
    if (end > base + BCAP) end = base + BCAP;
    hist[t] = 0;
    __syncthreads();
    for (int i = base + t; i < end; i += 256)
        atomicAdd(&hist[buck[i] >> 24], 1);
    __syncthreads();
    const int v = hist[t];
    scan[t] = v;
    __syncthreads();
    for (int d = 1; d < 256; d <<= 1) {
        int x = (t >= d) ? scan[t - d] : 0;
        __syncthreads();
        scan[t] += x;
        __syncthreads();
    }
    const int excl = scan[t] - v;        // bucket-local exclusive prefix
    const int node = b * NPB + t;
    if (node < NN) {
        offs[node] = base + excl;        // begin
        ends[node] = base + scan[t];     // end (inclusive prefix)
    }
    hist[t] = base + excl;               // cursor for this node
    __syncthreads();
    for (int i = base + t; i < end; i += 256) {
        const u32 pv = buck[i];
        const int p = atomicAdd(&hist[pv >> 24], 1);   // LDS atomic
        csr[p] = pv;                                    // keep packed
    }
}

__device__ __forceinline__ void acc8(float* a, uint4 r) {
    a[0] += bf2f(r.x); a[1] += bf2f(r.x >> 16);
    a[2] += bf2f(r.y); a[3] += bf2f(r.y >> 16);
    a[4] += bf2f(r.z); a[5] += bf2f(r.z >> 16);
    a[6] += bf2f(r.w); a[7] += bf2f(r.w >> 16);
}

// ---------------- fused SAGE layer (bf16 in): H = relu([X | mean_agg(X)] @ [Ws;Wn] + b) ----------------
// 512-thread blocks over a 64-node tile (R8 measured-best geometry).
// Phase A: 32 groups x 2 nodes; 8-edge straight-line batching (8 loads in
// flight per round — halves dependent latency rounds vs 4-batch; no branches).
// Phase B: MFMA tiling split across 8 waves (w>>1 = row stripe, w&1 = col half).
template<int CO, bool DUALOUT>
__global__ __launch_bounds__(512) void k_layer(const u16* __restrict__ Xb,
                                               const u16* __restrict__ WT,
                                               const int* __restrict__ offs,
                                               const int* __restrict__ ends,
                                               const u32* __restrict__ csr,
                                               const float* __restrict__ biasf,
                                               u16* __restrict__ Hb,
                                               float* __restrict__ Hf) {
    constexpr int K = 128, KV = 8, CT = CO / 16, CH = CT / 2, RS = K + 8;
    __shared__ __align__(16) u16 aggT[64 * RS];
    const int t = threadIdx.x, lane = t & 63, w = t >> 6;
    const int g = lane >> 4, f = lane & 15;     // group-in-wave 0..3, feature slot
    const int grp = w * 4 + g;                  // 0..31: owns nodes {grp*2, grp*2+1}
    const int rbase = blockIdx.x * 64;

    // phase A: pull-aggregate neighbor means into LDS (bf16)
    for (int i = 0; i < 2; ++i) {
        const int lrow = grp * 2 + i;
        const int node = rbase + lrow;
        float acc[8] = {0.f, 0.f, 0.f, 0.f, 0.f, 0.f, 0.f, 0.f};
        float sc = 0.f;
        if (node < NN) {
            int beg = offs[node], end = ends[node];
            if (beg < 0) beg = 0;
            if (end > EMAX) end = EMAX;
            if (end < beg) end = beg;
            sc = 1.0f / (float)max(end - beg, 1);
            int e = beg;
            for (; e + 8 <= end; e += 8) {       // 8 independent gathers in flight
                u32 p0 = csr[e],     p1 = csr[e + 1], p2 = csr[e + 2], p3 = csr[e + 3];
                u32 p4 = csr[e + 4], p5 = csr[e + 5], p6 = csr[e + 6], p7 = csr[e + 7];
                uint4 r0 = *(const uint4*)&Xb[(size_t)(p0 & 0xFFFFFFu) * K + f * 8];
                uint4 r1 = *(const uint4*)&Xb[(size_t)(p1 & 0xFFFFFFu) * K + f * 8];
                uint4 r2 = *(const uint4*)&Xb[(size_t)(p2 & 0xFFFFFFu) * K + f * 8];
                uint4 r3 = *(const uint4*)&Xb[(size_t)(p3 & 0xFFFFFFu) * K + f * 8];
                uint4 r4 = *(const uint4*)&Xb[(size_t)(p4 & 0xFFFFFFu) * K + f * 8];
                uint4 r5 = *(const uint4*)&Xb[(size_t)(p5 & 0xFFFFFFu) * K + f * 8];
                uint4 r6 = *(const uint4*)&Xb[(size_t)(p6 & 0xFFFFFFu) * K + f * 8];
                uint4 r7 = *(const uint4*)&Xb[(size_t)(p7 & 0xFFFFFFu) * K + f * 8];
                acc8(acc, r0); acc8(acc, r1); acc8(acc, r2); acc8(acc, r3);
                acc8(acc, r4); acc8(acc, r5); acc8(acc, r6); acc8(acc, r7);
            }
            for (; e + 4 <= end; e += 4) {
                u32 p0 = csr[e], p1 = csr[e + 1], p2 = csr[e + 2], p3 = csr[e + 3];
                uint4 r0 = *(const uint4*)&Xb[(size_t)(p0 & 0xFFFFFFu) * K + f * 8];
                uint4 r1 = *(const uint4*)&Xb[(size_t)(p1 & 0xFFFFFFu) * K + f * 8];
                uint4 r2 = *(const uint4*)&Xb[(size_t)(p2 & 0xFFFFFFu) * K + f * 8];
                uint4 r3 = *(const uint4*)&Xb[(size_t)(p3 & 0xFFFFFFu) * K + f * 8];
                acc8(acc, r0); acc8(acc, r1); acc8(acc, r2); acc8(acc, r3);
            }
            for (; e < end; ++e) {
                u32 p = csr[e];
                uint4 r = *(const uint4*)&Xb[(size_t)(p & 0xFFFFFFu) * K + f * 8];
                acc8(acc, r);
            }
        }
        uint4 o;
        o.x = pack2(acc[0] * sc, acc[1] * sc);
        o.y = pack2(acc[2] * sc, acc[3] * sc);
        o.z = pack2(acc[4] * sc, acc[5] * sc);
        o.w = pack2(acc[6] * sc, acc[7] * sc);
        *(uint4*)&aggT[lrow * RS + f * 8] = o;
    }
    __syncthreads();

    // phase B: MFMA over virtual K=256 ([x_row | agg_row]); 8 waves:
    // row stripe ws = w>>1, column half ch = w&1 (CH tiles each).
    const int nidx = lane & 15, quad = lane >> 4;
    const int ws = w >> 1, ch = w & 1;
    int arow = rbase + ws * 16 + nidx;
    if (arow > NN - 1) arow = NN - 1;          // clamped rows never stored
    const u16* xu = &Xb[(size_t)arow * K];
    const u16* grow = &aggT[(ws * 16 + nidx) * RS];
    f32x4 accv[CH] = {};
#pragma unroll
    for (int s = 0; s < KV; ++s) {
        s16x8 a = (s < 4) ? *(const s16x8*)&xu[s * 32 + quad * 8]
                          : *(const s16x8*)&grow[(s - 4) * 32 + quad * 8];
#pragma unroll
        for (int c = 0; c < CH; ++c) {
            const int cc = ch * CH + c;
            s16x8 b = *(const s16x8*)&WT[((cc * KV + s) * 64 + lane) * 8];
            accv[c] = __builtin_amdgcn_mfma_f32_16x16x32_bf16(a, b, accv[c], 0, 0, 0);
        }
    }
#pragma unroll
    for (int c = 0; c < CH; ++c) {
        const int col = (ch * CH + c) * 16 + nidx;
        float bv = biasf[col];
#pragma unroll
        for (int r = 0; r < 4; ++r) {
            int orow = rbase + ws * 16 + quad * 4 + r;
            if (orow < NN) {
                float hv = fmaxf(accv[c][r] + bv, 0.f);
                Hb[(size_t)orow * CO + col] = f2bf(hv);
                if (DUALOUT) Hf[(size_t)orow * CO + col] = hv;   // fp32 h output
            }
        }
    }
}

// ---------------- edge scoring via MFMA, 4 tiles (64 edges) per wave (R6/R8 measured-best) ----------------
__global__ __launch_bounds__(256) void k_edge(const u16* __restrict__ H2,
                                              const u16* __restrict__ WTM,
                                              const int* __restrict__ es, const int* __restrict__ ed,
                                              const float* __restrict__ blob,
                                              float* __restrict__ out) {
    const int t = threadIdx.x, lane = t & 63, w = t >> 6;
    const int nidx = lane & 15, quad = lane >> 4;
    const int base = blockIdx.x * 256 + w * 64;    // this wave: edges [base, base+64)

    // 8 independent index loads
    const u16* rs[4];
    const u16* rd[4];
#pragma unroll
    for (int tt = 0; tt < 4; ++tt) {
        const int e = base + tt * 16 + nidx;
        const int ns = clampi(es[e], NN - 1);
        const int nd = clampi(ed[e], NN - 1);
        rs[tt] = H2 + (size_t)ns * 64;
        rd[tt] = H2 + (size_t)nd * 64;
    }
    // 16 independent 16B gathers, all in flight together
    s16x8 a[4][4];
#pragma unroll
    for (int tt = 0; tt < 4; ++tt) {
        a[tt][0] = *(const s16x8*)&rs[tt][     quad * 8];
        a[tt][1] = *(const s16x8*)&rs[tt][32 + quad * 8];
        a[tt][2] = *(const s16x8*)&rd[tt][     quad * 8];
        a[tt][3] = *(const s16x8*)&rd[tt][32 + quad * 8];
    }

    float sum[4][4] = {};
#pragma unroll
    for (int c = 0; c < 8; ++c) {
        const s16x8 b0 = *(const s16x8*)&WTM[((c * 4 + 0) * 64 + lane) * 8];
        const s16x8 b1 = *(const s16x8*)&WTM[((c * 4 + 1) * 64 + lane) * 8];
        const s16x8 b2 = *(const s16x8*)&WTM[((c * 4 + 2) * 64 + lane) * 8];
        const s16x8 b3 = *(const s16x8*)&WTM[((c * 4 + 3) * 64 + lane) * 8];
        const int col = c * 16 + nidx;
        const float bb = blob[192 + col], ww = blob[320 + col];
#pragma unroll
        for (int tt = 0; tt < 4; ++tt) {
            f32x4 acc = {};
            acc = __builtin_amdgcn_mfma_f32_16x16x32_bf16(a[tt][0], b0, acc, 0, 0, 0);
            acc = __builtin_amdgcn_mfma_f32_16x16x32_bf16(a[tt][1], b1, acc, 0, 0, 0);
            acc = __builtin_amdgcn_mfma_f32_16x16x32_bf16(a[tt][2], b2, acc, 0, 0, 0);
            acc = __builtin_amdgcn_mfma_f32_16x16x32_bf16(a[tt][3], b3, acc, 0, 0, 0);
#pragma unroll
            for (int r = 0; r < 4; ++r)
                sum[tt][r] += fmaxf(acc[r] + bb, 0.f) * ww;
        }
    }

#pragma unroll
    for (int tt = 0; tt < 4; ++tt) {
#pragma unroll
        for (int r = 0; r < 4; ++r) {
            sum[tt][r] += __shfl_xor(sum[tt][r], 1, 64);
            sum[tt][r] += __shfl_xor(sum[tt][r], 2, 64);
            sum[tt][r] += __shfl_xor(sum[tt][r], 4, 64);
            sum[tt][r] += __shfl_xor(sum[tt][r], 8, 64);
        }
    }
    if (nidx == 0) {
        const float bb2 = blob[448];
#pragma unroll
        for (int tt = 0; tt < 4; ++tt) {
            f32x4 o;
#pragma unroll
            for (int r = 0; r < 4; ++r) {
                float x = sum[tt][r] + bb2;
                o[r] = 1.f / (1.f + __expf(-x));
            }
            *(f32x4*)&out[base + tt * 16 + quad * 4] = o;
        }
    }
}

extern "C" void kernel_launch(void* const* d_in, const int* in_sizes, int n_in,
                              void* d_out, int out_size, void* d_ws, size_t ws_size,
                              hipStream_t stream) {
    const float* X      = (const float*)d_in[0];
    const int*   esrc   = (const int*)d_in[1];
    const int*   edst   = (const int*)d_in[2];
    const int*   ssrc   = (const int*)d_in[3];
    const int*   sdst   = (const int*)d_in[4];
    const float* Wself1 = (const float*)d_in[5];
    const float* Wneigh1= (const float*)d_in[6];
    const float* b1     = (const float*)d_in[7];
    const float* Wself2 = (const float*)d_in[8];
    const float* Wneigh2= (const float*)d_in[9];
    const float* b2     = (const float*)d_in[10];
    const float* Wmlp1  = (const float*)d_in[11];
    const float* bmlp1  = (const float*)d_in[12];
    const float* Wmlp2  = (const float*)d_in[13];
    const float* bmlp2  = (const float*)d_in[14];

    // ---- workspace (ws_size >= 50 MB): peak 46.54 MB ----
    char* ws = (char*)d_ws;
    int*   offs = (int*)(ws + 0);             //   400,004 -> pad 400,128
    int*   ends = (int*)(ws + 400128);        //   400,000 -> pad 800,256
    u32*   csr  = (u32*)(ws + 800256);        // 7,206,912 (gapped, NB*BCAP) -> 8,007,168
    u16*   WTM  = (u16*)(ws + 8007168);       //    32,768 -> 8,039,936
    u16*   WT1  = (u16*)(ws + 8039936);       //    65,536 -> 8,105,472
    u16*   WT2  = (u16*)(ws + 8105472);       //    32,768 -> 8,138,240
    float* blob = (float*)(ws + 8138240);     //     1,796 -> pad 8,140,288
    u16*   H1   = (u16*)(ws + 8140288);       // 25,600,000 -> 33,740,288 (bf16 intern)
    u16*   H2b  = (u16*)(ws + 33740288);      // 12,800,000 -> 46,540,288 (bf16 copy of h)
    // bucket-sort scratch aliases H1 (dead before k_layer1 writes H1):
    u32*   buck = (u32*)(ws + 8140288);       // 7,206,912 -> 15,347,200
    int*   bcur = (int*)(ws + 15347200);      // 1,564

    // ---- OUTPUT: fp32 buffer, out_size=8M floats: [score 1.6M | h 6.4M] ----
    float* outScore = (float*)d_out;               // [EE2]
    float* Hf       = (float*)d_out + EE2;         // [NN*64]
    u16*   Xb       = (u16*)((char*)d_out + 6400000);   // 25.6 MB, ends at 32 MB

    k_pre<<<(NN * 128 / 4 + 255) / 256, 256, 0, stream>>>(
        X, Xb, Wself1, Wneigh1, Wself2, Wneigh2, Wmlp1, WT1, WT2, WTM,
        b1, b2, bmlp1, Wmlp2, bmlp2, blob, bcur);
    k_binA<<<NABLK, 256, 0, stream>>>(esrc, edst, bcur, buck);
    k_binB<<<NB, 256, 0, stream>>>(buck, bcur, offs, ends, csr);

    const int nblk = (NN + 63) / 64;
    k_layer<128, false><<<nblk, 512, 0, stream>>>(Xb, WT1, offs, ends, csr, blob,       H1,  nullptr);
    k_layer<64,  true> <<<nblk, 512, 0, stream>>>(H1, WT2, offs, ends, csr, blob + 128, H2b, Hf);
    k_edge<<<EE2 / 256, 256, 0, stream>>>(H2b, WTM, ssrc, sdst, blob, outScore);
}

// Round 12
// 441.032 us; speedup vs baseline: 1.0105x; 1.0076x over previous
//
#include <hip/hip_runtime.h>

#define NN  100000
#define EE1 1600000
#define EE2 1600000

#define NPB 256                          // nodes per bucket
#define NB  ((NN + NPB - 1) / NPB)       // 391 buckets
#define BCAP 4608                        // fixed slots per bucket (mean 4092 + 8 sigma)
#define EMAX (NB * BCAP)                 // 1,801,728 gapped csr slots
#define EPB 4096                         // edges per block (binA)
#define NABLK ((EE1 + EPB - 1) / EPB)    // 391 blocks

typedef unsigned short u16;
typedef unsigned int   u32;
typedef short s16x8 __attribute__((ext_vector_type(8)));
typedef float f32x4 __attribute__((ext_vector_type(4)));

__device__ __forceinline__ float bf2f(u32 u) {
    union { u32 i; float f; } v; v.i = (u & 0xffffu) << 16; return v.f;
}
__device__ __forceinline__ u16 f2bf(float f) {
    u32 x = __builtin_bit_cast(u32, f);
    return (u16)((x + 0x7fffu + ((x >> 16) & 1u)) >> 16);
}
__device__ __forceinline__ u32 pack2(float a, float b) {
    return (u32)f2bf(a) | ((u32)f2bf(b) << 16);
}
__device__ __forceinline__ int clampi(int v, int hi) {
    return v < 0 ? 0 : (v > hi ? hi : v);
}

// ---------------- fused preamble: X->bf16 cast + weight swizzle + bias blob + bcur init ----------------
__global__ void k_pre(const float* __restrict__ X, u16* __restrict__ Xb,
                      const float* __restrict__ Ws1, const float* __restrict__ Wn1,
                      const float* __restrict__ Ws2, const float* __restrict__ Wn2,
                      const float* __restrict__ Wm1,
                      u16* __restrict__ WT1, u16* __restrict__ WT2, u16* __restrict__ WTM,
                      const float* __restrict__ b1, const float* __restrict__ b2,
                      const float* __restrict__ bm1, const float* __restrict__ w2,
                      const float* __restrict__ b2m,
                      float* __restrict__ blob, int* __restrict__ bcur) {
    int i = blockIdx.x * 256 + threadIdx.x;
    if (i < NN * 128 / 4) {                   // cast: 4 elements per thread
        float4 v = *(const float4*)&X[i * 4];
        union { u16 h[4]; uint2 u; } o;
        o.h[0] = f2bf(v.x); o.h[1] = f2bf(v.y);
        o.h[2] = f2bf(v.z); o.h[3] = f2bf(v.w);
        *(uint2*)&Xb[i * 4] = o.u;
    }
    if (i < 65536) {                          // weight swizzle into MFMA B-fragment order
        if (i < 32768) {                      // WT1: Kv=256 ([Ws1;Wn1]), CO=128
            int f = i, j = f & 7, L = (f >> 3) & 63, t2 = f >> 9;
            int s = t2 & 7, c = t2 >> 3;
            int k = s * 32 + ((L >> 4) << 3) + j, co = (c << 4) + (L & 15);
            WT1[f] = f2bf((k < 128) ? Ws1[k * 128 + co] : Wn1[(k - 128) * 128 + co]);
        } else if (i < 49152) {               // WT2: Kv=256 ([Ws2;Wn2]), CO=64
            int f = i - 32768, j = f & 7, L = (f >> 3) & 63, t2 = f >> 9;
            int s = t2 & 7, c = t2 >> 3;
            int k = s * 32 + ((L >> 4) << 3) + j, co = (c << 4) + (L & 15);
            WT2[f] = f2bf((k < 128) ? Ws2[k * 64 + co] : Wn2[(k - 128) * 64 + co]);
        } else {                              // WTM: K=128, CO=128 (Wmlp1 straight)
            int f = i - 49152, j = f & 7, L = (f >> 3) & 63, t2 = f >> 9;
            int s = t2 & 3, c = t2 >> 2;
            int k = s * 32 + ((L >> 4) << 3) + j, co = (c << 4) + (L & 15);
            WTM[f] = f2bf(Wm1[k * 128 + co]);
        }
    }
    if (i < NB) bcur[i] = i * BCAP;           // fixed bucket bases
    if (i < 449) {                            // bias blob
        if (i < 128)      blob[i] = b1[i];
        else if (i < 192) blob[i] = b2[i - 128];
        else if (i < 320) blob[i] = bm1[i - 192];
        else if (i < 448) blob[i] = w2[i - 320];
        else              blob[i] = b2m[0];
    }
}

// ================= CSR build: fixed-capacity buckets (no global scan) =================

// ---- A: scatter edges into fixed bucket regions, block-reserved runs ----
// packed entry: (dst & 255) << 24 | src   (src <= NN-1 < 2^24)
__global__ __launch_bounds__(256) void k_binA(const int* __restrict__ es,
                                              const int* __restrict__ ed,
                                              int* __restrict__ bucketCur,
                                              u32* __restrict__ buck) {
    __shared__ int hist[NB];
    __shared__ int base[NB];
    const int t = threadIdx.x;
    for (int i = t; i < NB; i += 256) hist[i] = 0;
    __syncthreads();
    const int e0 = blockIdx.x * EPB;
    const int e1 = min(e0 + EPB, EE1);
    for (int e = e0 + t; e < e1; e += 256)
        atomicAdd(&hist[clampi(ed[e], NN - 1) >> 8], 1);
    __syncthreads();
    for (int i = t; i < NB; i += 256) {
        const int h = hist[i];
        base[i] = h ? atomicAdd(&bucketCur[i], h) : 0;   // reserve contiguous run
        hist[i] = 0;                                     // reuse as running cursor
    }
    __syncthreads();
    for (int e = e0 + t; e < e1; e += 256) {
        const int d = clampi(ed[e], NN - 1);
        const int s = clampi(es[e], NN - 1);
        const int b = d >> 8;
        const int p = base[b] + atomicAdd(&hist[b], 1);
        if (p < (b + 1) * BCAP)                          // 8-sigma overflow guard
            buck[p] = ((u32)(d & 255) << 24) | (u32)s;
    }
}

// ---- B: per-bucket CSR fill + offs/ends. csr keeps the PACKED entry.
__global__ __launch_bounds__(256) void k_binB(const u32* __restrict__ buck,
                                              const int* __restrict__ bcur,
                                              int* __restrict__ offs,
                                              int* __restrict__ ends,
                                              u32* __restrict__ csr) {
    __shared__ int hist[NPB];
    __shared__ int scan[NPB];
    const int t = threadIdx.x;
    const int b = blockIdx.x;
    const int base = b * BCAP;
    int end = bcur[b];
    if (end > base + BCAP) end = base + BCAP;
    hist[t] = 0;
    __syncthreads();
    for (int i = base + t; i < end; i += 256)
        atomicAdd(&hist[buck[i] >> 24], 1);
    __syncthreads();
    const int v = hist[t];
    scan[t] = v;
    __syncthreads();
    for (int d = 1; d < 256; d <<= 1) {
        int x = (t >= d) ? scan[t - d] : 0;
        __syncthreads();
        scan[t] += x;
        __syncthreads();
    }
    const int excl = scan[t] - v;        // bucket-local exclusive prefix
    const int node = b * NPB + t;
    if (node < NN) {
        offs[node] = base + excl;        // begin
        ends[node] = base + scan[t];     // end (inclusive prefix)
    }
    hist[t] = base + excl;               // cursor for this node
    __syncthreads();
    for (int i = base + t; i < end; i += 256) {
        const u32 pv = buck[i];
        const int p = atomicAdd(&hist[pv >> 24], 1);   // LDS atomic
        csr[p] = pv;                                    // keep packed
    }
}

__device__ __forceinline__ void acc8(float* a, uint4 r) {
    a[0] += bf2f(r.x); a[1] += bf2f(r.x >> 16);
    a[2] += bf2f(r.y); a[3] += bf2f(r.y >> 16);
    a[4] += bf2f(r.z); a[5] += bf2f(r.z >> 16);
    a[6] += bf2f(r.w); a[7] += bf2f(r.w >> 16);
}

// ---------------- fused SAGE layer (bf16 in): H = relu([X | mean_agg(X)] @ [Ws;Wn] + b) ----------------
// 512-thread blocks over a 64-node tile (R8 measured-best, byte-identical loop).
// Phase A: 32 groups x 2 nodes, unconditional 4-edge batching.
// Phase B: MFMA tiling split across 8 waves (w>>1 = row stripe, w&1 = col half).
template<int CO, bool DUALOUT>
__global__ __launch_bounds__(512) void k_layer(const u16* __restrict__ Xb,
                                               const u16* __restrict__ WT,
                                               const int* __restrict__ offs,
                                               const int* __restrict__ ends,
                                               const u32* __restrict__ csr,
                                               const float* __restrict__ biasf,
                                               u16* __restrict__ Hb,
                                               float* __restrict__ Hf) {
    constexpr int K = 128, KV = 8, CT = CO / 16, CH = CT / 2, RS = K + 8;
    __shared__ __align__(16) u16 aggT[64 * RS];
    const int t = threadIdx.x, lane = t & 63, w = t >> 6;
    const int g = lane >> 4, f = lane & 15;     // group-in-wave 0..3, feature slot
    const int grp = w * 4 + g;                  // 0..31: owns nodes {grp*2, grp*2+1}
    const int rbase = blockIdx.x * 64;

    // phase A: pull-aggregate neighbor means into LDS (bf16)
    for (int i = 0; i < 2; ++i) {
        const int lrow = grp * 2 + i;
        const int node = rbase + lrow;
        float acc[8] = {0.f, 0.f, 0.f, 0.f, 0.f, 0.f, 0.f, 0.f};
        float sc = 0.f;
        if (node < NN) {
            int beg = offs[node], end = ends[node];
            if (beg < 0) beg = 0;
            if (end > EMAX) end = EMAX;
            if (end < beg) end = beg;
            sc = 1.0f / (float)max(end - beg, 1);
            int e = beg;
            for (; e + 4 <= end; e += 4) {
                u32 p0 = csr[e], p1 = csr[e + 1], p2 = csr[e + 2], p3 = csr[e + 3];
                uint4 r0 = *(const uint4*)&Xb[(size_t)(p0 & 0xFFFFFFu) * K + f * 8];
                uint4 r1 = *(const uint4*)&Xb[(size_t)(p1 & 0xFFFFFFu) * K + f * 8];
                uint4 r2 = *(const uint4*)&Xb[(size_t)(p2 & 0xFFFFFFu) * K + f * 8];
                uint4 r3 = *(const uint4*)&Xb[(size_t)(p3 & 0xFFFFFFu) * K + f * 8];
                acc8(acc, r0); acc8(acc, r1); acc8(acc, r2); acc8(acc, r3);
            }
            for (; e < end; ++e) {
                u32 p = csr[e];
                uint4 r = *(const uint4*)&Xb[(size_t)(p & 0xFFFFFFu) * K + f * 8];
                acc8(acc, r);
            }
        }
        uint4 o;
        o.x = pack2(acc[0] * sc, acc[1] * sc);
        o.y = pack2(acc[2] * sc, acc[3] * sc);
        o.z = pack2(acc[4] * sc, acc[5] * sc);
        o.w = pack2(acc[6] * sc, acc[7] * sc);
        *(uint4*)&aggT[lrow * RS + f * 8] = o;
    }
    __syncthreads();

    // phase B: MFMA over virtual K=256 ([x_row | agg_row]); 8 waves:
    // row stripe ws = w>>1, column half ch = w&1 (CH tiles each).
    const int nidx = lane & 15, quad = lane >> 4;
    const int ws = w >> 1, ch = w & 1;
    int arow = rbase + ws * 16 + nidx;
    if (arow > NN - 1) arow = NN - 1;          // clamped rows never stored
    const u16* xu = &Xb[(size_t)arow * K];
    const u16* grow = &aggT[(ws * 16 + nidx) * RS];
    f32x4 accv[CH] = {};
#pragma unroll
    for (int s = 0; s < KV; ++s) {
        s16x8 a = (s < 4) ? *(const s16x8*)&xu[s * 32 + quad * 8]
                          : *(const s16x8*)&grow[(s - 4) * 32 + quad * 8];
#pragma unroll
        for (int c = 0; c < CH; ++c) {
            const int cc = ch * CH + c;
            s16x8 b = *(const s16x8*)&WT[((cc * KV + s) * 64 + lane) * 8];
            accv[c] = __builtin_amdgcn_mfma_f32_16x16x32_bf16(a, b, accv[c], 0, 0, 0);
        }
    }
#pragma unroll
    for (int c = 0; c < CH; ++c) {
        const int col = (ch * CH + c) * 16 + nidx;
        float bv = biasf[col];
#pragma unroll
        for (int r = 0; r < 4; ++r) {
            int orow = rbase + ws * 16 + quad * 4 + r;
            if (orow < NN) {
                float hv = fmaxf(accv[c][r] + bv, 0.f);
                Hb[(size_t)orow * CO + col] = f2bf(hv);
                if (DUALOUT) Hf[(size_t)orow * CO + col] = hv;   // fp32 h output
            }
        }
    }
}

// ---------------- edge scoring via MFMA, 8 tiles (128 edges) per wave ----------------
// In-flight scaling experiment: 32 A-fragment gathers issued up-front per lane
// set (vs 16), index loads amortized 2x. u32 element offsets keep addr regs low.
__global__ __launch_bounds__(256) void k_edge(const u16* __restrict__ H2,
                                              const u16* __restrict__ WTM,
                                              const int* __restrict__ es, const int* __restrict__ ed,
                                              const float* __restrict__ blob,
                                              float* __restrict__ out) {
    const int t = threadIdx.x, lane = t & 63, w = t >> 6;
    const int nidx = lane & 15, quad = lane >> 4;
    const int base = blockIdx.x * 512 + w * 128;   // this wave: edges [base, base+128)

    // 16 independent index loads -> u32 element offsets
    u32 offS[8], offD[8];
#pragma unroll
    for (int tt = 0; tt < 8; ++tt) {
        const int e = base + tt * 16 + nidx;
        offS[tt] = (u32)clampi(es[e], NN - 1) * 64u;
        offD[tt] = (u32)clampi(ed[e], NN - 1) * 64u;
    }
    // 32 independent 16B gathers, all in flight together
    s16x8 a[8][4];
#pragma unroll
    for (int tt = 0; tt < 8; ++tt) {
        a[tt][0] = *(const s16x8*)&H2[offS[tt] +      quad * 8];
        a[tt][1] = *(const s16x8*)&H2[offS[tt] + 32 + quad * 8];
        a[tt][2] = *(const s16x8*)&H2[offD[tt] +      quad * 8];
        a[tt][3] = *(const s16x8*)&H2[offD[tt] + 32 + quad * 8];
    }

    float sum[8][4] = {};
#pragma unroll
    for (int c = 0; c < 8; ++c) {
        const s16x8 b0 = *(const s16x8*)&WTM[((c * 4 + 0) * 64 + lane) * 8];
        const s16x8 b1 = *(const s16x8*)&WTM[((c * 4 + 1) * 64 + lane) * 8];
        const s16x8 b2 = *(const s16x8*)&WTM[((c * 4 + 2) * 64 + lane) * 8];
        const s16x8 b3 = *(const s16x8*)&WTM[((c * 4 + 3) * 64 + lane) * 8];
        const int col = c * 16 + nidx;
        const float bb = blob[192 + col], ww = blob[320 + col];
#pragma unroll
        for (int tt = 0; tt < 8; ++tt) {
            f32x4 acc = {};
            acc = __builtin_amdgcn_mfma_f32_16x16x32_bf16(a[tt][0], b0, acc, 0, 0, 0);
            acc = __builtin_amdgcn_mfma_f32_16x16x32_bf16(a[tt][1], b1, acc, 0, 0, 0);
            acc = __builtin_amdgcn_mfma_f32_16x16x32_bf16(a[tt][2], b2, acc, 0, 0, 0);
            acc = __builtin_amdgcn_mfma_f32_16x16x32_bf16(a[tt][3], b3, acc, 0, 0, 0);
#pragma unroll
            for (int r = 0; r < 4; ++r)
                sum[tt][r] += fmaxf(acc[r] + bb, 0.f) * ww;
        }
    }

#pragma unroll
    for (int tt = 0; tt < 8; ++tt) {
#pragma unroll
        for (int r = 0; r < 4; ++r) {
            sum[tt][r] += __shfl_xor(sum[tt][r], 1, 64);
            sum[tt][r] += __shfl_xor(sum[tt][r], 2, 64);
            sum[tt][r] += __shfl_xor(sum[tt][r], 4, 64);
            sum[tt][r] += __shfl_xor(sum[tt][r], 8, 64);
        }
    }
    if (nidx == 0) {
        const float bb2 = blob[448];
#pragma unroll
        for (int tt = 0; tt < 8; ++tt) {
            f32x4 o;
#pragma unroll
            for (int r = 0; r < 4; ++r) {
                float x = sum[tt][r] + bb2;
                o[r] = 1.f / (1.f + __expf(-x));
            }
            *(f32x4*)&out[base + tt * 16 + quad * 4] = o;
        }
    }
}

extern "C" void kernel_launch(void* const* d_in, const int* in_sizes, int n_in,
                              void* d_out, int out_size, void* d_ws, size_t ws_size,
                              hipStream_t stream) {
    const float* X      = (const float*)d_in[0];
    const int*   esrc   = (const int*)d_in[1];
    const int*   edst   = (const int*)d_in[2];
    const int*   ssrc   = (const int*)d_in[3];
    const int*   sdst   = (const int*)d_in[4];
    const float* Wself1 = (const float*)d_in[5];
    const float* Wneigh1= (const float*)d_in[6];
    const float* b1     = (const float*)d_in[7];
    const float* Wself2 = (const float*)d_in[8];
    const float* Wneigh2= (const float*)d_in[9];
    const float* b2     = (const float*)d_in[10];
    const float* Wmlp1  = (const float*)d_in[11];
    const float* bmlp1  = (const float*)d_in[12];
    const float* Wmlp2  = (const float*)d_in[13];
    const float* bmlp2  = (const float*)d_in[14];

    // ---- workspace (ws_size >= 50 MB): peak 46.54 MB ----
    char* ws = (char*)d_ws;
    int*   offs = (int*)(ws + 0);             //   400,004 -> pad 400,128
    int*   ends = (int*)(ws + 400128);        //   400,000 -> pad 800,256
    u32*   csr  = (u32*)(ws + 800256);        // 7,206,912 (gapped, NB*BCAP) -> 8,007,168
    u16*   WTM  = (u16*)(ws + 8007168);       //    32,768 -> 8,039,936
    u16*   WT1  = (u16*)(ws + 8039936);       //    65,536 -> 8,105,472
    u16*   WT2  = (u16*)(ws + 8105472);       //    32,768 -> 8,138,240
    float* blob = (float*)(ws + 8138240);     //     1,796 -> pad 8,140,288
    u16*   H1   = (u16*)(ws + 8140288);       // 25,600,000 -> 33,740,288 (bf16 intern)
    u16*   H2b  = (u16*)(ws + 33740288);      // 12,800,000 -> 46,540,288 (bf16 copy of h)
    // bucket-sort scratch aliases H1 (dead before k_layer1 writes H1):
    u32*   buck = (u32*)(ws + 8140288);       // 7,206,912 -> 15,347,200
    int*   bcur = (int*)(ws + 15347200);      // 1,564

    // ---- OUTPUT: fp32 buffer, out_size=8M floats: [score 1.6M | h 6.4M] ----
    float* outScore = (float*)d_out;               // [EE2]
    float* Hf       = (float*)d_out + EE2;         // [NN*64]
    u16*   Xb       = (u16*)((char*)d_out + 6400000);   // 25.6 MB, ends at 32 MB

    k_pre<<<(NN * 128 / 4 + 255) / 256, 256, 0, stream>>>(
        X, Xb, Wself1, Wneigh1, Wself2, Wneigh2, Wmlp1, WT1, WT2, WTM,
        b1, b2, bmlp1, Wmlp2, bmlp2, blob, bcur);
    k_binA<<<NABLK, 256, 0, stream>>>(esrc, edst, bcur, buck);
    k_binB<<<NB, 256, 0, stream>>>(buck, bcur, offs, ends, csr);

    const int nblk = (NN + 63) / 64;
    k_layer<128, false><<<nblk, 512, 0, stream>>>(Xb, WT1, offs, ends, csr, blob,       H1,  nullptr);
    k_layer<64,  true> <<<nblk, 512, 0, stream>>>(H1, WT2, offs, ends, csr, blob + 128, H2b, Hf);
    k_edge<<<EE2 / 512, 256, 0, stream>>>(H2b, WTM, ssrc, sdst, blob, outScore);
}

// Round 13
// 427.601 us; speedup vs baseline: 1.0423x; 1.0314x over previous
//
#include <hip/hip_runtime.h>

#define NN  100000
#define EE1 1600000
#define EE2 1600000

#define NPB 256                          // nodes per bucket
#define NB  ((NN + NPB - 1) / NPB)       // 391 buckets
#define BCAP 4608                        // fixed slots per bucket (mean 4092 + 8 sigma)
#define EMAX (NB * BCAP)                 // 1,801,728 gapped csr slots
#define EPB 4096                         // edges per block (binA)
#define NABLK ((EE1 + EPB - 1) / EPB)    // 391 blocks

typedef unsigned short u16;
typedef unsigned int   u32;
typedef short s16x8 __attribute__((ext_vector_type(8)));
typedef float f32x4 __attribute__((ext_vector_type(4)));

__device__ __forceinline__ float bf2f(u32 u) {
    union { u32 i; float f; } v; v.i = (u & 0xffffu) << 16; return v.f;
}
__device__ __forceinline__ u16 f2bf(float f) {
    u32 x = __builtin_bit_cast(u32, f);
    return (u16)((x + 0x7fffu + ((x >> 16) & 1u)) >> 16);
}
__device__ __forceinline__ u32 pack2(float a, float b) {
    return (u32)f2bf(a) | ((u32)f2bf(b) << 16);
}
__device__ __forceinline__ int clampi(int v, int hi) {
    return v < 0 ? 0 : (v > hi ? hi : v);
}

// ---------------- fused preamble: X->bf16 cast + weight swizzle + bias blob + bcur init ----------------
__global__ void k_pre(const float* __restrict__ X, u16* __restrict__ Xb,
                      const float* __restrict__ Ws1, const float* __restrict__ Wn1,
                      const float* __restrict__ Ws2, const float* __restrict__ Wn2,
                      const float* __restrict__ Wm1,
                      u16* __restrict__ WT1, u16* __restrict__ WT2, u16* __restrict__ WTM,
                      const float* __restrict__ b1, const float* __restrict__ b2,
                      const float* __restrict__ bm1, const float* __restrict__ w2,
                      const float* __restrict__ b2m,
                      float* __restrict__ blob, int* __restrict__ bcur) {
    int i = blockIdx.x * 256 + threadIdx.x;
    if (i < NN * 128 / 4) {                   // cast: 4 elements per thread
        float4 v = *(const float4*)&X[i * 4];
        union { u16 h[4]; uint2 u; } o;
        o.h[0] = f2bf(v.x); o.h[1] = f2bf(v.y);
        o.h[2] = f2bf(v.z); o.h[3] = f2bf(v.w);
        *(uint2*)&Xb[i * 4] = o.u;
    }
    if (i < 65536) {                          // weight swizzle into MFMA B-fragment order
        if (i < 32768) {                      // WT1: Kv=256 ([Ws1;Wn1]), CO=128
            int f = i, j = f & 7, L = (f >> 3) & 63, t2 = f >> 9;
            int s = t2 & 7, c = t2 >> 3;
            int k = s * 32 + ((L >> 4) << 3) + j, co = (c << 4) + (L & 15);
            WT1[f] = f2bf((k < 128) ? Ws1[k * 128 + co] : Wn1[(k - 128) * 128 + co]);
        } else if (i < 49152) {               // WT2: Kv=256 ([Ws2;Wn2]), CO=64
            int f = i - 32768, j = f & 7, L = (f >> 3) & 63, t2 = f >> 9;
            int s = t2 & 7, c = t2 >> 3;
            int k = s * 32 + ((L >> 4) << 3) + j, co = (c << 4) + (L & 15);
            WT2[f] = f2bf((k < 128) ? Ws2[k * 64 + co] : Wn2[(k - 128) * 64 + co]);
        } else {                              // WTM: K=128, CO=128 (Wmlp1 straight)
            int f = i - 49152, j = f & 7, L = (f >> 3) & 63, t2 = f >> 9;
            int s = t2 & 3, c = t2 >> 2;
            int k = s * 32 + ((L >> 4) << 3) + j, co = (c << 4) + (L & 15);
            WTM[f] = f2bf(Wm1[k * 128 + co]);
        }
    }
    if (i < NB) bcur[i] = i * BCAP;           // fixed bucket bases
    if (i < 449) {                            // bias blob
        if (i < 128)      blob[i] = b1[i];
        else if (i < 192) blob[i] = b2[i - 128];
        else if (i < 320) blob[i] = bm1[i - 192];
        else if (i < 448) blob[i] = w2[i - 320];
        else              blob[i] = b2m[0];
    }
}

// ================= CSR build: fixed-capacity buckets (no global scan) =================

// ---- A: scatter edges into fixed bucket regions, block-reserved runs ----
// packed entry: (dst & 255) << 24 | src   (src <= NN-1 < 2^24)
__global__ __launch_bounds__(256) void k_binA(const int* __restrict__ es,
                                              const int* __restrict__ ed,
                                              int* __restrict__ bucketCur,
                                              u32* __restrict__ buck) {
    __shared__ int hist[NB];
    __shared__ int base[NB];
    const int t = threadIdx.x;
    for (int i = t; i < NB; i += 256) hist[i] = 0;
    __syncthreads();
    const int e0 = blockIdx.x * EPB;
    const int e1 = min(e0 + EPB, EE1);
    for (int e = e0 + t; e < e1; e += 256)
        atomicAdd(&hist[clampi(ed[e], NN - 1) >> 8], 1);
    __syncthreads();
    for (int i = t; i < NB; i += 256) {
        const int h = hist[i];
        base[i] = h ? atomicAdd(&bucketCur[i], h) : 0;   // reserve contiguous run
        hist[i] = 0;                                     // reuse as running cursor
    }
    __syncthreads();
    for (int e = e0 + t; e < e1; e += 256) {
        const int d = clampi(ed[e], NN - 1);
        const int s = clampi(es[e], NN - 1);
        const int b = d >> 8;
        const int p = base[b] + atomicAdd(&hist[b], 1);
        if (p < (b + 1) * BCAP)                          // 8-sigma overflow guard
            buck[p] = ((u32)(d & 255) << 24) | (u32)s;
    }
}

// ---- B: per-bucket CSR fill + offs/ends. csr keeps the PACKED entry.
__global__ __launch_bounds__(256) void k_binB(const u32* __restrict__ buck,
                                              const int* __restrict__ bcur,
                                              int* __restrict__ offs,
                                              int* __restrict__ ends,
                                              u32* __restrict__ csr) {
    __shared__ int hist[NPB];
    __shared__ int scan[NPB];
    const int t = threadIdx.x;
    const int b = blockIdx.x;
    const int base = b * BCAP;
    int end = bcur[b];
    if (end > base + BCAP) end = base + BCAP;
    hist[t] = 0;
    __syncthreads();
    for (int i = base + t; i < end; i += 256)
        atomicAdd(&hist[buck[i] >> 24], 1);
    __syncthreads();
    const int v = hist[t];
    scan[t] = v;
    __syncthreads();
    for (int d = 1; d < 256; d <<= 1) {
        int x = (t >= d) ? scan[t - d] : 0;
        __syncthreads();
        scan[t] += x;
        __syncthreads();
    }
    const int excl = scan[t] - v;        // bucket-local exclusive prefix
    const int node = b * NPB + t;
    if (node < NN) {
        offs[node] = base + excl;        // begin
        ends[node] = base + scan[t];     // end (inclusive prefix)
    }
    hist[t] = base + excl;               // cursor for this node
    __syncthreads();
    for (int i = base + t; i < end; i += 256) {
        const u32 pv = buck[i];
        const int p = atomicAdd(&hist[pv >> 24], 1);   // LDS atomic
        csr[p] = pv;                                    // keep packed
    }
}

__device__ __forceinline__ void acc8(float* a, uint4 r) {
    a[0] += bf2f(r.x); a[1] += bf2f(r.x >> 16);
    a[2] += bf2f(r.y); a[3] += bf2f(r.y >> 16);
    a[4] += bf2f(r.z); a[5] += bf2f(r.z >> 16);
    a[6] += bf2f(r.w); a[7] += bf2f(r.w >> 16);
}

// ---------------- fused SAGE layer (bf16 in): H = relu([X | mean_agg(X)] @ [Ws;Wn] + b) ----------------
// 512-thread blocks over a 64-node tile (measured-best geometry, R8).
// Phase A: 32 groups x 2 nodes, unconditional 4-edge batching.
// Phase B: MFMA tiling split across 8 waves (w>>1 = row stripe, w&1 = col half).
template<int CO, bool DUALOUT>
__global__ __launch_bounds__(512) void k_layer(const u16* __restrict__ Xb,
                                               const u16* __restrict__ WT,
                                               const int* __restrict__ offs,
                                               const int* __restrict__ ends,
                                               const u32* __restrict__ csr,
                                               const float* __restrict__ biasf,
                                               u16* __restrict__ Hb,
                                               float* __restrict__ Hf) {
    constexpr int K = 128, KV = 8, CT = CO / 16, CH = CT / 2, RS = K + 8;
    __shared__ __align__(16) u16 aggT[64 * RS];
    const int t = threadIdx.x, lane = t & 63, w = t >> 6;
    const int g = lane >> 4, f = lane & 15;     // group-in-wave 0..3, feature slot
    const int grp = w * 4 + g;                  // 0..31: owns nodes {grp*2, grp*2+1}
    const int rbase = blockIdx.x * 64;

    // phase A: pull-aggregate neighbor means into LDS (bf16)
    for (int i = 0; i < 2; ++i) {
        const int lrow = grp * 2 + i;
        const int node = rbase + lrow;
        float acc[8] = {0.f, 0.f, 0.f, 0.f, 0.f, 0.f, 0.f, 0.f};
        float sc = 0.f;
        if (node < NN) {
            int beg = offs[node], end = ends[node];
            if (beg < 0) beg = 0;
            if (end > EMAX) end = EMAX;
            if (end < beg) end = beg;
            sc = 1.0f / (float)max(end - beg, 1);
            int e = beg;
            for (; e + 4 <= end; e += 4) {
                u32 p0 = csr[e], p1 = csr[e + 1], p2 = csr[e + 2], p3 = csr[e + 3];
                uint4 r0 = *(const uint4*)&Xb[(size_t)(p0 & 0xFFFFFFu) * K + f * 8];
                uint4 r1 = *(const uint4*)&Xb[(size_t)(p1 & 0xFFFFFFu) * K + f * 8];
                uint4 r2 = *(const uint4*)&Xb[(size_t)(p2 & 0xFFFFFFu) * K + f * 8];
                uint4 r3 = *(const uint4*)&Xb[(size_t)(p3 & 0xFFFFFFu) * K + f * 8];
                acc8(acc, r0); acc8(acc, r1); acc8(acc, r2); acc8(acc, r3);
            }
            for (; e < end; ++e) {
                u32 p = csr[e];
                uint4 r = *(const uint4*)&Xb[(size_t)(p & 0xFFFFFFu) * K + f * 8];
                acc8(acc, r);
            }
        }
        uint4 o;
        o.x = pack2(acc[0] * sc, acc[1] * sc);
        o.y = pack2(acc[2] * sc, acc[3] * sc);
        o.z = pack2(acc[4] * sc, acc[5] * sc);
        o.w = pack2(acc[6] * sc, acc[7] * sc);
        *(uint4*)&aggT[lrow * RS + f * 8] = o;
    }
    __syncthreads();

    // phase B: MFMA over virtual K=256 ([x_row | agg_row]); 8 waves:
    // row stripe ws = w>>1, column half ch = w&1 (CH tiles each).
    const int nidx = lane & 15, quad = lane >> 4;
    const int ws = w >> 1, ch = w & 1;
    int arow = rbase + ws * 16 + nidx;
    if (arow > NN - 1) arow = NN - 1;          // clamped rows never stored
    const u16* xu = &Xb[(size_t)arow * K];
    const u16* grow = &aggT[(ws * 16 + nidx) * RS];
    f32x4 accv[CH] = {};
#pragma unroll
    for (int s = 0; s < KV; ++s) {
        s16x8 a = (s < 4) ? *(const s16x8*)&xu[s * 32 + quad * 8]
                          : *(const s16x8*)&grow[(s - 4) * 32 + quad * 8];
#pragma unroll
        for (int c = 0; c < CH; ++c) {
            const int cc = ch * CH + c;
            s16x8 b = *(const s16x8*)&WT[((cc * KV + s) * 64 + lane) * 8];
            accv[c] = __builtin_amdgcn_mfma_f32_16x16x32_bf16(a, b, accv[c], 0, 0, 0);
        }
    }
#pragma unroll
    for (int c = 0; c < CH; ++c) {
        const int col = (ch * CH + c) * 16 + nidx;
        float bv = biasf[col];
#pragma unroll
        for (int r = 0; r < 4; ++r) {
            int orow = rbase + ws * 16 + quad * 4 + r;
            if (orow < NN) {
                float hv = fmaxf(accv[c][r] + bv, 0.f);
                Hb[(size_t)orow * CO + col] = f2bf(hv);
                if (DUALOUT) Hf[(size_t)orow * CO + col] = hv;   // fp32 h output
            }
        }
    }
}

// ---------------- edge scoring via MFMA, 4 tiles (64 edges) per wave (measured-best, R6/R8) ----------------
__global__ __launch_bounds__(256) void k_edge(const u16* __restrict__ H2,
                                              const u16* __restrict__ WTM,
                                              const int* __restrict__ es, const int* __restrict__ ed,
                                              const float* __restrict__ blob,
                                              float* __restrict__ out) {
    const int t = threadIdx.x, lane = t & 63, w = t >> 6;
    const int nidx = lane & 15, quad = lane >> 4;
    const int base = blockIdx.x * 256 + w * 64;    // this wave: edges [base, base+64)

    // 8 independent index loads
    const u16* rs[4];
    const u16* rd[4];
#pragma unroll
    for (int tt = 0; tt < 4; ++tt) {
        const int e = base + tt * 16 + nidx;
        const int ns = clampi(es[e], NN - 1);
        const int nd = clampi(ed[e], NN - 1);
        rs[tt] = H2 + (size_t)ns * 64;
        rd[tt] = H2 + (size_t)nd * 64;
    }
    // 16 independent 16B gathers, all in flight together
    s16x8 a[4][4];
#pragma unroll
    for (int tt = 0; tt < 4; ++tt) {
        a[tt][0] = *(const s16x8*)&rs[tt][     quad * 8];
        a[tt][1] = *(const s16x8*)&rs[tt][32 + quad * 8];
        a[tt][2] = *(const s16x8*)&rd[tt][     quad * 8];
        a[tt][3] = *(const s16x8*)&rd[tt][32 + quad * 8];
    }

    float sum[4][4] = {};
#pragma unroll
    for (int c = 0; c < 8; ++c) {
        const s16x8 b0 = *(const s16x8*)&WTM[((c * 4 + 0) * 64 + lane) * 8];
        const s16x8 b1 = *(const s16x8*)&WTM[((c * 4 + 1) * 64 + lane) * 8];
        const s16x8 b2 = *(const s16x8*)&WTM[((c * 4 + 2) * 64 + lane) * 8];
        const s16x8 b3 = *(const s16x8*)&WTM[((c * 4 + 3) * 64 + lane) * 8];
        const int col = c * 16 + nidx;
        const float bb = blob[192 + col], ww = blob[320 + col];
#pragma unroll
        for (int tt = 0; tt < 4; ++tt) {
            f32x4 acc = {};
            acc = __builtin_amdgcn_mfma_f32_16x16x32_bf16(a[tt][0], b0, acc, 0, 0, 0);
            acc = __builtin_amdgcn_mfma_f32_16x16x32_bf16(a[tt][1], b1, acc, 0, 0, 0);
            acc = __builtin_amdgcn_mfma_f32_16x16x32_bf16(a[tt][2], b2, acc, 0, 0, 0);
            acc = __builtin_amdgcn_mfma_f32_16x16x32_bf16(a[tt][3], b3, acc, 0, 0, 0);
#pragma unroll
            for (int r = 0; r < 4; ++r)
                sum[tt][r] += fmaxf(acc[r] + bb, 0.f) * ww;
        }
    }

#pragma unroll
    for (int tt = 0; tt < 4; ++tt) {
#pragma unroll
        for (int r = 0; r < 4; ++r) {
            sum[tt][r] += __shfl_xor(sum[tt][r], 1, 64);
            sum[tt][r] += __shfl_xor(sum[tt][r], 2, 64);
            sum[tt][r] += __shfl_xor(sum[tt][r], 4, 64);
            sum[tt][r] += __shfl_xor(sum[tt][r], 8, 64);
        }
    }
    if (nidx == 0) {
        const float bb2 = blob[448];
#pragma unroll
        for (int tt = 0; tt < 4; ++tt) {
            f32x4 o;
#pragma unroll
            for (int r = 0; r < 4; ++r) {
                float x = sum[tt][r] + bb2;
                o[r] = 1.f / (1.f + __expf(-x));
            }
            *(f32x4*)&out[base + tt * 16 + quad * 4] = o;
        }
    }
}

extern "C" void kernel_launch(void* const* d_in, const int* in_sizes, int n_in,
                              void* d_out, int out_size, void* d_ws, size_t ws_size,
                              hipStream_t stream) {
    const float* X      = (const float*)d_in[0];
    const int*   esrc   = (const int*)d_in[1];
    const int*   edst   = (const int*)d_in[2];
    const int*   ssrc   = (const int*)d_in[3];
    const int*   sdst   = (const int*)d_in[4];
    const float* Wself1 = (const float*)d_in[5];
    const float* Wneigh1= (const float*)d_in[6];
    const float* b1     = (const float*)d_in[7];
    const float* Wself2 = (const float*)d_in[8];
    const float* Wneigh2= (const float*)d_in[9];
    const float* b2     = (const float*)d_in[10];
    const float* Wmlp1  = (const float*)d_in[11];
    const float* bmlp1  = (const float*)d_in[12];
    const float* Wmlp2  = (const float*)d_in[13];
    const float* bmlp2  = (const float*)d_in[14];

    // ---- workspace (ws_size >= 50 MB): peak 46.54 MB ----
    char* ws = (char*)d_ws;
    int*   offs = (int*)(ws + 0);             //   400,004 -> pad 400,128
    int*   ends = (int*)(ws + 400128);        //   400,000 -> pad 800,256
    u32*   csr  = (u32*)(ws + 800256);        // 7,206,912 (gapped, NB*BCAP) -> 8,007,168
    u16*   WTM  = (u16*)(ws + 8007168);       //    32,768 -> 8,039,936
    u16*   WT1  = (u16*)(ws + 8039936);       //    65,536 -> 8,105,472
    u16*   WT2  = (u16*)(ws + 8105472);       //    32,768 -> 8,138,240
    float* blob = (float*)(ws + 8138240);     //     1,796 -> pad 8,140,288
    u16*   H1   = (u16*)(ws + 8140288);       // 25,600,000 -> 33,740,288 (bf16 intern)
    u16*   H2b  = (u16*)(ws + 33740288);      // 12,800,000 -> 46,540,288 (bf16 copy of h)
    // bucket-sort scratch aliases H1 (dead before k_layer1 writes H1):
    u32*   buck = (u32*)(ws + 8140288);       // 7,206,912 -> 15,347,200
    int*   bcur = (int*)(ws + 15347200);      // 1,564

    // ---- OUTPUT: fp32 buffer, out_size=8M floats: [score 1.6M | h 6.4M] ----
    float* outScore = (float*)d_out;               // [EE2]
    float* Hf       = (float*)d_out + EE2;         // [NN*64]
    u16*   Xb       = (u16*)((char*)d_out + 6400000);   // 25.6 MB, ends at 32 MB

    k_pre<<<(NN * 128 / 4 + 255) / 256, 256, 0, stream>>>(
        X, Xb, Wself1, Wneigh1, Wself2, Wneigh2, Wmlp1, WT1, WT2, WTM,
        b1, b2, bmlp1, Wmlp2, bmlp2, blob, bcur);
    k_binA<<<NABLK, 256, 0, stream>>>(esrc, edst, bcur, buck);
    k_binB<<<NB, 256, 0, stream>>>(buck, bcur, offs, ends, csr);

    const int nblk = (NN + 63) / 64;
    k_layer<128, false><<<nblk, 512, 0, stream>>>(Xb, WT1, offs, ends, csr, blob,       H1,  nullptr);
    k_layer<64,  true> <<<nblk, 512, 0, stream>>>(H1, WT2, offs, ends, csr, blob + 128, H2b, Hf);
    k_edge<<<EE2 / 256, 256, 0, stream>>>(H2b, WTM, ssrc, sdst, blob, outScore);
}